// Round 6
// baseline (443.839 us; speedup 1.0000x reference)
//
#include <hip/hip_runtime.h>

// B=32, DIM=4096, NH=32, NKV=8, HD=128, MAXLEN=4096, START_POS=4095. All fp32.
// HBM floor: KV 1GB + weights 160MB ~= 190us @6.3TB/s.
#define QSCALE 0.08838834764831845f   // 1/sqrt(128)

// ws layout (floats):
//  part_qkv [16][32][6144] @ 0          (3145728)
//  qc_g     [32][4096]     @ 3145728    (131072)   roped+scaled q
//  kn_g     [32][1024]     @ 3276800    (32768)    roped new k
//  vn_g     [32][1024]     @ 3309568    (32768)    new v
//  pmss     [32768][2]     @ 3342336    (65536)
//  pacc     [32768][128]   @ 3407872    (4194304)
//  a_ws     [32][4096]     @ 7602176    (131072)
//  part_out [16][32][4096] @ 7733248    (2097152)

// ---------------------------------------------------------------------------
// GEMV: part[ks][n][m0+..] = sum over 256-k slice of W[m][k]*X[n][k].
// (unchanged since round 3)
// ---------------------------------------------------------------------------
#define GEMM_FMA(r, wf) \
    acc[r][0] = fmaf(wf.x, x0.x, acc[r][0]); acc[r][0] = fmaf(wf.y, x0.y, acc[r][0]); \
    acc[r][0] = fmaf(wf.z, x0.z, acc[r][0]); acc[r][0] = fmaf(wf.w, x0.w, acc[r][0]); \
    acc[r][1] = fmaf(wf.x, x1.x, acc[r][1]); acc[r][1] = fmaf(wf.y, x1.y, acc[r][1]); \
    acc[r][1] = fmaf(wf.z, x1.z, acc[r][1]); acc[r][1] = fmaf(wf.w, x1.w, acc[r][1]); \
    acc[r][2] = fmaf(wf.x, x2.x, acc[r][2]); acc[r][2] = fmaf(wf.y, x2.y, acc[r][2]); \
    acc[r][2] = fmaf(wf.z, x2.z, acc[r][2]); acc[r][2] = fmaf(wf.w, x2.w, acc[r][2]); \
    acc[r][3] = fmaf(wf.x, x3.x, acc[r][3]); acc[r][3] = fmaf(wf.y, x3.y, acc[r][3]); \
    acc[r][3] = fmaf(wf.z, x3.z, acc[r][3]); acc[r][3] = fmaf(wf.w, x3.w, acc[r][3]);

__device__ __forceinline__ void gemv3(
    const float* __restrict__ W,      // pre-offset: row 0 == output column m0
    const float* __restrict__ X,
    float* __restrict__ part, const int M, const int m0, const int ks)
{
    const int t = threadIdx.x;
    const int ksub = t & 3;
    const int ngrp = (t >> 2) & 7;
    const int mgrp = t >> 5;

    const int kbase = ks * 256 + ksub * 4;
    const float* wr0 = W + (size_t)(mgrp * 8 + 0) * 4096 + kbase;
    const float* wr1 = W + (size_t)(mgrp * 8 + 1) * 4096 + kbase;
    const float* wr2 = W + (size_t)(mgrp * 8 + 2) * 4096 + kbase;
    const float* wr3 = W + (size_t)(mgrp * 8 + 3) * 4096 + kbase;
    const float* wr4 = W + (size_t)(mgrp * 8 + 4) * 4096 + kbase;
    const float* wr5 = W + (size_t)(mgrp * 8 + 5) * 4096 + kbase;
    const float* wr6 = W + (size_t)(mgrp * 8 + 6) * 4096 + kbase;
    const float* wr7 = W + (size_t)(mgrp * 8 + 7) * 4096 + kbase;
    const float* xr0 = X + (size_t)(ngrp * 4 + 0) * 4096 + kbase;
    const float* xr1 = X + (size_t)(ngrp * 4 + 1) * 4096 + kbase;
    const float* xr2 = X + (size_t)(ngrp * 4 + 2) * 4096 + kbase;
    const float* xr3 = X + (size_t)(ngrp * 4 + 3) * 4096 + kbase;

    float acc[8][4];
#pragma unroll
    for (int r = 0; r < 8; ++r)
#pragma unroll
        for (int n = 0; n < 4; ++n) acc[r][n] = 0.f;

#pragma unroll 2
    for (int c = 0; c < 16; ++c) {
        const int off = c * 16;
        const float4 w0 = *(const float4*)(wr0 + off);
        const float4 w1 = *(const float4*)(wr1 + off);
        const float4 w2 = *(const float4*)(wr2 + off);
        const float4 w3 = *(const float4*)(wr3 + off);
        const float4 w4 = *(const float4*)(wr4 + off);
        const float4 w5 = *(const float4*)(wr5 + off);
        const float4 w6 = *(const float4*)(wr6 + off);
        const float4 w7 = *(const float4*)(wr7 + off);
        const float4 x0 = *(const float4*)(xr0 + off);
        const float4 x1 = *(const float4*)(xr1 + off);
        const float4 x2 = *(const float4*)(xr2 + off);
        const float4 x3 = *(const float4*)(xr3 + off);
        GEMM_FMA(0, w0) GEMM_FMA(1, w1) GEMM_FMA(2, w2) GEMM_FMA(3, w3)
        GEMM_FMA(4, w4) GEMM_FMA(5, w5) GEMM_FMA(6, w6) GEMM_FMA(7, w7)
    }

#pragma unroll
    for (int r = 0; r < 8; ++r)
#pragma unroll
        for (int n = 0; n < 4; ++n) {
            acc[r][n] += __shfl_xor(acc[r][n], 1);
            acc[r][n] += __shfl_xor(acc[r][n], 2);
        }

    if (ksub == 0) {
        float* base = part + (size_t)ks * 32 * M + m0 + mgrp * 8;
#pragma unroll
        for (int n = 0; n < 4; ++n) {
            float* dst = base + (size_t)(ngrp * 4 + n) * M;
            *(float4*)(dst)     = make_float4(acc[0][n], acc[1][n], acc[2][n], acc[3][n]);
            *(float4*)(dst + 4) = make_float4(acc[4][n], acc[5][n], acc[6][n], acc[7][n]);
        }
    }
}

__global__ __launch_bounds__(256, 4) void gemv_qkv_kernel(
    const float* __restrict__ wq, const float* __restrict__ wk,
    const float* __restrict__ wv, const float* __restrict__ x,
    float* __restrict__ part)     // [16][32][6144]
{
    const int mb = blockIdx.x >> 4, ks = blockIdx.x & 15;
    const int m0 = mb * 64;
    const float* W;
    if (m0 < 4096)      W = wq + (size_t)m0 * 4096;
    else if (m0 < 5120) W = wk + (size_t)(m0 - 4096) * 4096;
    else                W = wv + (size_t)(m0 - 5120) * 4096;
    gemv3(W, x, part, 6144, m0, ks);
}

__global__ __launch_bounds__(256, 4) void gemv_out_kernel(
    const float* __restrict__ wo, const float* __restrict__ a_ws,
    float* __restrict__ part)     // [16][32][4096]
{
    const int mb = blockIdx.x >> 4, ks = blockIdx.x & 15;
    gemv3(wo + (size_t)(mb * 64) * 4096, a_ws, part, 4096, mb * 64, ks);
}

// ---------------------------------------------------------------------------
// qkv combine: sum 16 k-split partials; rope+scale q, rope new k, copy new v.
// ---------------------------------------------------------------------------
__global__ __launch_bounds__(256) void qkv_combine_kernel(
    const float* __restrict__ part,   // [16][32][6144]
    const float* __restrict__ freqs,  // [128]
    float* __restrict__ qc_g, float* __restrict__ kn_g, float* __restrict__ vn_g)
{
    const int idx = blockIdx.x * 256 + threadIdx.x;   // f4 index, 49152 total
    const int b = idx / 1536;
    const int cm = (idx - b * 1536) * 4;              // column within 6144
    const float* p = part + (size_t)b * 6144 + cm;
    float4 v = make_float4(0.f, 0.f, 0.f, 0.f);
#pragma unroll
    for (int s = 0; s < 16; ++s) {
        const float4 a = *(const float4*)(p + (size_t)s * (32 * 6144));
        v.x += a.x; v.y += a.y; v.z += a.z; v.w += a.w;
    }
    if (cm < 4096) {
        const int d = cm & 127;
        const float4 f = *(const float4*)(freqs + d);
        float4 o;
        o.x = (v.x * f.x - v.y * f.y) * QSCALE;
        o.y = (v.x * f.y + v.y * f.x) * QSCALE;
        o.z = (v.z * f.z - v.w * f.w) * QSCALE;
        o.w = (v.z * f.w + v.w * f.z) * QSCALE;
        *(float4*)(qc_g + (size_t)b * 4096 + cm) = o;
    } else if (cm < 5120) {
        const int d = (cm - 4096) & 127;
        const float4 f = *(const float4*)(freqs + d);
        float4 o;
        o.x = v.x * f.x - v.y * f.y;
        o.y = v.x * f.y + v.y * f.x;
        o.z = v.z * f.z - v.w * f.w;
        o.w = v.z * f.w + v.w * f.z;
        *(float4*)(kn_g + (size_t)b * 1024 + (cm - 4096)) = o;
    } else {
        *(float4*)(vn_g + (size_t)b * 1024 + (cm - 5120)) = v;
    }
}

// ---------------------------------------------------------------------------
// Attention v6: head-slot-permuted softmax. Same mapping as v4:
// grid 1024: bid=(b*16+split)*2+q2; 256 thr = 4 waves; wave w: gsub=w>>1,
// rsub=w&1; lane: g2=lane>>5, j=lane&31; g=q2*4+gsub*2+g2; 128 rows/wave.
// Per row: 8 shfl (levels 1,2 x4 heads) -> select own head (o3=j&3, 3 sel)
// -> 3 shfl finish -> softmax for ONE head (1 exp) -> 3 shfl pe-broadcast
// -> 16 acc fma into head-permuted slots (slot s <-> head o3^s).
// DS 20->14/row, exp 4->1/row, softmax VALU ~1/4. 24 waves/CU.
// ---------------------------------------------------------------------------
__global__ __launch_bounds__(256, 6) void attn6_kernel(
    const float* __restrict__ qc_g, const float* __restrict__ kn_g,
    const float* __restrict__ vn_g,
    const float* __restrict__ cache_k, const float* __restrict__ cache_v,
    float* __restrict__ pmss, float* __restrict__ pacc)
{
    const int t = threadIdx.x;
    const int w = t >> 6, lane = t & 63;
    const int g2 = lane >> 5, j = lane & 31;
    const int o3 = j & 3;
    const int bid = blockIdx.x;
    const int q2 = bid & 1, split = (bid >> 1) & 15, b = bid >> 5;
    const int gsub = w >> 1, rsub = w & 1;
    const int g = q2 * 4 + gsub * 2 + g2;
    const int row0 = split * 256 + rsub * 128;

    float4 q[4];
    const float* qb = qc_g + (size_t)b * 4096 + (size_t)g * 512 + j * 4;
#pragma unroll
    for (int h = 0; h < 4; ++h) q[h] = *(const float4*)(qb + h * 128);

    float m_s = -1e30f, ss_s = 0.f;
    float4 acc[4];   // slot s holds head (o3^s)
#pragma unroll
    for (int s = 0; s < 4; ++s) acc[s] = make_float4(0.f, 0.f, 0.f, 0.f);

    auto process = [&](const float4 kf, const float4 vf) {
        float d[4];
#pragma unroll
        for (int h = 0; h < 4; ++h)
            d[h] = fmaf(q[h].x, kf.x, fmaf(q[h].y, kf.y,
                   fmaf(q[h].z, kf.z, q[h].w * kf.w)));
        d[0] += __shfl_xor(d[0], 1); d[1] += __shfl_xor(d[1], 1);
        d[2] += __shfl_xor(d[2], 1); d[3] += __shfl_xor(d[3], 1);
        d[0] += __shfl_xor(d[0], 2); d[1] += __shfl_xor(d[1], 2);
        d[2] += __shfl_xor(d[2], 2); d[3] += __shfl_xor(d[3], 2);
        // select this lane's head (o3): static 2-bit select, no scratch
        const float t0 = (o3 & 1) ? d[1] : d[0];
        const float t1 = (o3 & 1) ? d[3] : d[2];
        float dsc = (o3 & 2) ? t1 : t0;
        dsc += __shfl_xor(dsc, 4);
        dsc += __shfl_xor(dsc, 8);
        dsc += __shfl_xor(dsc, 16);
        // online softmax for ONE head; rescale path rare (wave-any)
        if (__any(dsc - m_s > 8.0f)) {
            const float nm = fmaxf(m_s, dsc);
            const float c  = __expf(m_s - nm);
            m_s = nm; ss_s *= c;
            const float c1 = __shfl_xor(c, 1);
            const float c2 = __shfl_xor(c, 2);
            const float c3 = __shfl_xor(c1, 2);
            acc[0].x *= c;  acc[0].y *= c;  acc[0].z *= c;  acc[0].w *= c;
            acc[1].x *= c1; acc[1].y *= c1; acc[1].z *= c1; acc[1].w *= c1;
            acc[2].x *= c2; acc[2].y *= c2; acc[2].z *= c2; acc[2].w *= c2;
            acc[3].x *= c3; acc[3].y *= c3; acc[3].z *= c3; acc[3].w *= c3;
        }
        const float pe = __expf(dsc - m_s);   // <= e^8
        ss_s += pe;
        const float p1 = __shfl_xor(pe, 1);
        const float p2 = __shfl_xor(pe, 2);
        const float p3 = __shfl_xor(p1, 2);
        acc[0].x = fmaf(pe, vf.x, acc[0].x); acc[0].y = fmaf(pe, vf.y, acc[0].y);
        acc[0].z = fmaf(pe, vf.z, acc[0].z); acc[0].w = fmaf(pe, vf.w, acc[0].w);
        acc[1].x = fmaf(p1, vf.x, acc[1].x); acc[1].y = fmaf(p1, vf.y, acc[1].y);
        acc[1].z = fmaf(p1, vf.z, acc[1].z); acc[1].w = fmaf(p1, vf.w, acc[1].w);
        acc[2].x = fmaf(p2, vf.x, acc[2].x); acc[2].y = fmaf(p2, vf.y, acc[2].y);
        acc[2].z = fmaf(p2, vf.z, acc[2].z); acc[2].w = fmaf(p2, vf.w, acc[2].w);
        acc[3].x = fmaf(p3, vf.x, acc[3].x); acc[3].y = fmaf(p3, vf.y, acc[3].y);
        acc[3].z = fmaf(p3, vf.z, acc[3].z); acc[3].w = fmaf(p3, vf.w, acc[3].w);
    };

    const size_t cbase = ((size_t)b * 4096 + row0) * 1024 + (size_t)g * 128 + j * 4;
    const float* kp = cache_k + cbase;
    const float* vp = cache_v + cbase;

    const bool lastw = (split == 15) && (rsub == 1);   // owns row 4095
    const int n = lastw ? 127 : 128;

    // zero-mov 4-slot ping-pong pipeline (as round 4)
    float4 kA, vA, kB, vB, kC, vC, kD, vD;
    kA = *(const float4*)(kp);        vA = *(const float4*)(vp);
    kB = *(const float4*)(kp + 1024); vB = *(const float4*)(vp + 1024);
    int i = 0;
    for (; i + 4 <= n; i += 4) {
        const float* k2 = kp + (size_t)(i + 2) * 1024;
        const float* v2 = vp + (size_t)(i + 2) * 1024;
        kC = *(const float4*)(k2);        vC = *(const float4*)(v2);
        kD = *(const float4*)(k2 + 1024); vD = *(const float4*)(v2 + 1024);
        process(kA, vA);
        process(kB, vB);
        if (i + 6 <= n) {
            const float* k4 = kp + (size_t)(i + 4) * 1024;
            const float* v4 = vp + (size_t)(i + 4) * 1024;
            kA = *(const float4*)(k4);        vA = *(const float4*)(v4);
            kB = *(const float4*)(k4 + 1024); vB = *(const float4*)(v4 + 1024);
        } else if (i + 5 <= n) {
            const float* k4 = kp + (size_t)(i + 4) * 1024;
            const float* v4 = vp + (size_t)(i + 4) * 1024;
            kA = *(const float4*)(k4); vA = *(const float4*)(v4);
        }
        process(kC, vC);
        process(kD, vD);
    }
    if (i < n)     process(kA, vA);
    if (i + 1 < n) process(kB, vB);
    if (i + 2 < n) {
        const float4 kf = *(const float4*)(kp + (size_t)(i + 2) * 1024);
        const float4 vf = *(const float4*)(vp + (size_t)(i + 2) * 1024);
        process(kf, vf);
    }
    if (lastw) {   // row 4095: freshly roped new-token k / new v
        const float4 kf = *(const float4*)(kn_g + (size_t)b * 1024 + (size_t)g * 128 + j * 4);
        const float4 vf = *(const float4*)(vn_g + (size_t)b * 1024 + (size_t)g * 128 + j * 4);
        process(kf, vf);
    }

    // partials: idx = (((b*16+split)*2+rsub)*8 + g)*4 + h; un-permute slots
    const int pidx = (((b * 16 + split) * 2 + rsub) * 8 + g) * 4;
#pragma unroll
    for (int s = 0; s < 4; ++s) {
        const int head = o3 ^ s;
        *(float4*)(pacc + (size_t)(pidx + head) * 128 + j * 4) = acc[s];
    }
    if (j < 4) {   // lane o3==j holds head j's (m, ss)
        pmss[(size_t)(pidx + j) * 2]     = m_s;
        pmss[(size_t)(pidx + j) * 2 + 1] = ss_s;
    }
}

// ---------------------------------------------------------------------------
// Merge 32 partials per (b,g,h). Block=(b,g), 128 thr: h=t>>5, jj=t&31.
// ---------------------------------------------------------------------------
__global__ __launch_bounds__(128) void attn_combine_kernel(
    const float* __restrict__ pmss, const float* __restrict__ pacc,
    float* __restrict__ a_ws)
{
    const int bg = blockIdx.x, t = threadIdx.x;
    const int h = t >> 5, jj = t & 31;
    const int b = bg >> 3, g = bg & 7;

    float M = -1e30f;
#pragma unroll
    for (int s = 0; s < 16; ++s)
#pragma unroll
        for (int r = 0; r < 2; ++r) {
            const int idx = (((b * 16 + s) * 2 + r) * 8 + g) * 4 + h;
            M = fmaxf(M, pmss[(size_t)idx * 2]);
        }
    float SS = 0.f;
    float4 o = make_float4(0.f, 0.f, 0.f, 0.f);
#pragma unroll
    for (int s = 0; s < 16; ++s)
#pragma unroll
        for (int r = 0; r < 2; ++r) {
            const int idx = (((b * 16 + s) * 2 + r) * 8 + g) * 4 + h;
            const float wgt = __expf(pmss[(size_t)idx * 2] - M);
            SS = fmaf(pmss[(size_t)idx * 2 + 1], wgt, SS);
            const float4 a = *(const float4*)(pacc + (size_t)idx * 128 + jj * 4);
            o.x = fmaf(a.x, wgt, o.x);
            o.y = fmaf(a.y, wgt, o.y);
            o.z = fmaf(a.z, wgt, o.z);
            o.w = fmaf(a.w, wgt, o.w);
        }
    const float inv = 1.f / SS;
    o.x *= inv; o.y *= inv; o.z *= inv; o.w *= inv;
    *(float4*)&a_ws[(size_t)b * 4096 + (size_t)(g * 4 + h) * 128 + jj * 4] = o;
}

__global__ __launch_bounds__(256) void out_combine_kernel(
    const float* __restrict__ part, float* __restrict__ out)
{
    const int i4 = (blockIdx.x * 256 + threadIdx.x) * 4;
    float4 v = make_float4(0.f, 0.f, 0.f, 0.f);
#pragma unroll
    for (int s = 0; s < 16; ++s) {
        const float4 a = *(const float4*)(part + (size_t)s * 131072 + i4);
        v.x += a.x; v.y += a.y; v.z += a.z; v.w += a.w;
    }
    *(float4*)(out + i4) = v;
}

extern "C" void kernel_launch(void* const* d_in, const int* in_sizes, int n_in,
                              void* d_out, int out_size, void* d_ws, size_t ws_size,
                              hipStream_t stream)
{
    const float* x       = (const float*)d_in[0];
    const float* freqs   = (const float*)d_in[1];
    const float* cache_k = (const float*)d_in[2];
    const float* cache_v = (const float*)d_in[3];
    const float* wq      = (const float*)d_in[4];
    const float* wk      = (const float*)d_in[5];
    const float* wv      = (const float*)d_in[6];
    const float* wo      = (const float*)d_in[7];

    float* out = (float*)d_out;
    float* ws  = (float*)d_ws;
    float* part_qkv = ws;                    // 3145728
    float* qc_g     = ws + 3145728;          // 131072
    float* kn_g     = ws + 3276800;          // 32768
    float* vn_g     = ws + 3309568;          // 32768
    float* pmss     = ws + 3342336;          // 65536
    float* pacc     = ws + 3407872;          // 4194304
    float* a_ws     = ws + 7602176;          // 131072
    float* part_out = ws + 7733248;          // 2097152

    gemv_qkv_kernel<<<1536, 256, 0, stream>>>(wq, wk, wv, x, part_qkv);
    qkv_combine_kernel<<<192, 256, 0, stream>>>(part_qkv, freqs, qc_g, kn_g, vn_g);
    attn6_kernel<<<1024, 256, 0, stream>>>(qc_g, kn_g, vn_g, cache_k, cache_v, pmss, pacc);
    attn_combine_kernel<<<256, 128, 0, stream>>>(pmss, pacc, a_ws);
    gemv_out_kernel<<<1024, 256, 0, stream>>>(wo, a_ws, part_out);
    out_combine_kernel<<<128, 256, 0, stream>>>(part_out, out);
}

// Round 8
// 280.025 us; speedup vs baseline: 1.5850x; 1.5850x over previous
//
#include <hip/hip_runtime.h>

// B=32, DIM=4096, NH=32, NKV=8, HD=128, MAXLEN=4096, START_POS=4095. All fp32.
// HBM floor: KV 1GB + weights 160MB ~= 190us @6.3TB/s.
#define QSCALE 0.08838834764831845f   // 1/sqrt(128)

// ws layout (floats):
//  part_qkv [16][32][6144] @ 0          (3145728)
//  qc_g     [32][4096]     @ 3145728    (131072)   roped+scaled q
//  kn_g     [32][1024]     @ 3276800    (32768)    roped new k
//  vn_g     [32][1024]     @ 3309568    (32768)    new v
//  pmss     [32768][2]     @ 3342336    (65536)
//  pacc     [32768][128]   @ 3407872    (4194304)
//  a_ws     [32][4096]     @ 7602176    (131072)
//  part_out [16][32][4096] @ 7733248    (2097152)

typedef float f32x4 __attribute__((ext_vector_type(4)));

__device__ __forceinline__ float4 ntload4(const float* p) {
    const f32x4 v = __builtin_nontemporal_load((const f32x4*)p);
    return make_float4(v.x, v.y, v.z, v.w);
}

// ---------------------------------------------------------------------------
// GEMV: part[ks][n][m0+..] = sum over 256-k slice of W[m][k]*X[n][k].
// (unchanged since round 3)
// ---------------------------------------------------------------------------
#define GEMM_FMA(r, wf) \
    acc[r][0] = fmaf(wf.x, x0.x, acc[r][0]); acc[r][0] = fmaf(wf.y, x0.y, acc[r][0]); \
    acc[r][0] = fmaf(wf.z, x0.z, acc[r][0]); acc[r][0] = fmaf(wf.w, x0.w, acc[r][0]); \
    acc[r][1] = fmaf(wf.x, x1.x, acc[r][1]); acc[r][1] = fmaf(wf.y, x1.y, acc[r][1]); \
    acc[r][1] = fmaf(wf.z, x1.z, acc[r][1]); acc[r][1] = fmaf(wf.w, x1.w, acc[r][1]); \
    acc[r][2] = fmaf(wf.x, x2.x, acc[r][2]); acc[r][2] = fmaf(wf.y, x2.y, acc[r][2]); \
    acc[r][2] = fmaf(wf.z, x2.z, acc[r][2]); acc[r][2] = fmaf(wf.w, x2.w, acc[r][2]); \
    acc[r][3] = fmaf(wf.x, x3.x, acc[r][3]); acc[r][3] = fmaf(wf.y, x3.y, acc[r][3]); \
    acc[r][3] = fmaf(wf.z, x3.z, acc[r][3]); acc[r][3] = fmaf(wf.w, x3.w, acc[r][3]);

__device__ __forceinline__ void gemv3(
    const float* __restrict__ W,      // pre-offset: row 0 == output column m0
    const float* __restrict__ X,
    float* __restrict__ part, const int M, const int m0, const int ks)
{
    const int t = threadIdx.x;
    const int ksub = t & 3;
    const int ngrp = (t >> 2) & 7;
    const int mgrp = t >> 5;

    const int kbase = ks * 256 + ksub * 4;
    const float* wr0 = W + (size_t)(mgrp * 8 + 0) * 4096 + kbase;
    const float* wr1 = W + (size_t)(mgrp * 8 + 1) * 4096 + kbase;
    const float* wr2 = W + (size_t)(mgrp * 8 + 2) * 4096 + kbase;
    const float* wr3 = W + (size_t)(mgrp * 8 + 3) * 4096 + kbase;
    const float* wr4 = W + (size_t)(mgrp * 8 + 4) * 4096 + kbase;
    const float* wr5 = W + (size_t)(mgrp * 8 + 5) * 4096 + kbase;
    const float* wr6 = W + (size_t)(mgrp * 8 + 6) * 4096 + kbase;
    const float* wr7 = W + (size_t)(mgrp * 8 + 7) * 4096 + kbase;
    const float* xr0 = X + (size_t)(ngrp * 4 + 0) * 4096 + kbase;
    const float* xr1 = X + (size_t)(ngrp * 4 + 1) * 4096 + kbase;
    const float* xr2 = X + (size_t)(ngrp * 4 + 2) * 4096 + kbase;
    const float* xr3 = X + (size_t)(ngrp * 4 + 3) * 4096 + kbase;

    float acc[8][4];
#pragma unroll
    for (int r = 0; r < 8; ++r)
#pragma unroll
        for (int n = 0; n < 4; ++n) acc[r][n] = 0.f;

#pragma unroll 2
    for (int c = 0; c < 16; ++c) {
        const int off = c * 16;
        const float4 w0 = *(const float4*)(wr0 + off);
        const float4 w1 = *(const float4*)(wr1 + off);
        const float4 w2 = *(const float4*)(wr2 + off);
        const float4 w3 = *(const float4*)(wr3 + off);
        const float4 w4 = *(const float4*)(wr4 + off);
        const float4 w5 = *(const float4*)(wr5 + off);
        const float4 w6 = *(const float4*)(wr6 + off);
        const float4 w7 = *(const float4*)(wr7 + off);
        const float4 x0 = *(const float4*)(xr0 + off);
        const float4 x1 = *(const float4*)(xr1 + off);
        const float4 x2 = *(const float4*)(xr2 + off);
        const float4 x3 = *(const float4*)(xr3 + off);
        GEMM_FMA(0, w0) GEMM_FMA(1, w1) GEMM_FMA(2, w2) GEMM_FMA(3, w3)
        GEMM_FMA(4, w4) GEMM_FMA(5, w5) GEMM_FMA(6, w6) GEMM_FMA(7, w7)
    }

#pragma unroll
    for (int r = 0; r < 8; ++r)
#pragma unroll
        for (int n = 0; n < 4; ++n) {
            acc[r][n] += __shfl_xor(acc[r][n], 1);
            acc[r][n] += __shfl_xor(acc[r][n], 2);
        }

    if (ksub == 0) {
        float* base = part + (size_t)ks * 32 * M + m0 + mgrp * 8;
#pragma unroll
        for (int n = 0; n < 4; ++n) {
            float* dst = base + (size_t)(ngrp * 4 + n) * M;
            *(float4*)(dst)     = make_float4(acc[0][n], acc[1][n], acc[2][n], acc[3][n]);
            *(float4*)(dst + 4) = make_float4(acc[4][n], acc[5][n], acc[6][n], acc[7][n]);
        }
    }
}

__global__ __launch_bounds__(256, 4) void gemv_qkv_kernel(
    const float* __restrict__ wq, const float* __restrict__ wk,
    const float* __restrict__ wv, const float* __restrict__ x,
    float* __restrict__ part)     // [16][32][6144]
{
    const int mb = blockIdx.x >> 4, ks = blockIdx.x & 15;
    const int m0 = mb * 64;
    const float* W;
    if (m0 < 4096)      W = wq + (size_t)m0 * 4096;
    else if (m0 < 5120) W = wk + (size_t)(m0 - 4096) * 4096;
    else                W = wv + (size_t)(m0 - 5120) * 4096;
    gemv3(W, x, part, 6144, m0, ks);
}

__global__ __launch_bounds__(256, 4) void gemv_out_kernel(
    const float* __restrict__ wo, const float* __restrict__ a_ws,
    float* __restrict__ part)     // [16][32][4096]
{
    const int mb = blockIdx.x >> 4, ks = blockIdx.x & 15;
    gemv3(wo + (size_t)(mb * 64) * 4096, a_ws, part, 4096, mb * 64, ks);
}

// ---------------------------------------------------------------------------
// qkv combine: sum 16 k-split partials; rope+scale q, rope new k, copy new v.
// ---------------------------------------------------------------------------
__global__ __launch_bounds__(256) void qkv_combine_kernel(
    const float* __restrict__ part,   // [16][32][6144]
    const float* __restrict__ freqs,  // [128]
    float* __restrict__ qc_g, float* __restrict__ kn_g, float* __restrict__ vn_g)
{
    const int idx = blockIdx.x * 256 + threadIdx.x;   // f4 index, 49152 total
    const int b = idx / 1536;
    const int cm = (idx - b * 1536) * 4;              // column within 6144
    const float* p = part + (size_t)b * 6144 + cm;
    float4 v = make_float4(0.f, 0.f, 0.f, 0.f);
#pragma unroll
    for (int s = 0; s < 16; ++s) {
        const float4 a = *(const float4*)(p + (size_t)s * (32 * 6144));
        v.x += a.x; v.y += a.y; v.z += a.z; v.w += a.w;
    }
    if (cm < 4096) {
        const int d = cm & 127;
        const float4 f = *(const float4*)(freqs + d);
        float4 o;
        o.x = (v.x * f.x - v.y * f.y) * QSCALE;
        o.y = (v.x * f.y + v.y * f.x) * QSCALE;
        o.z = (v.z * f.z - v.w * f.w) * QSCALE;
        o.w = (v.z * f.w + v.w * f.z) * QSCALE;
        *(float4*)(qc_g + (size_t)b * 4096 + cm) = o;
    } else if (cm < 5120) {
        const int d = (cm - 4096) & 127;
        const float4 f = *(const float4*)(freqs + d);
        float4 o;
        o.x = v.x * f.x - v.y * f.y;
        o.y = v.x * f.y + v.y * f.x;
        o.z = v.z * f.z - v.w * f.w;
        o.w = v.z * f.w + v.w * f.z;
        *(float4*)(kn_g + (size_t)b * 1024 + (cm - 4096)) = o;
    } else {
        *(float4*)(vn_g + (size_t)b * 1024 + (cm - 5120)) = v;
    }
}

// ---------------------------------------------------------------------------
// Attention v7b: v6's head-slot-permuted softmax with the occupancy pragma
// FIXED ((256,4): VGPR budget 128, no spill; grid gives 16 waves/CU) and
// nontemporal K/V stream loads (via ext_vector_type, builtin-compatible).
// grid 1024: bid=(b*16+split)*2+q2; 256 thr = 4 waves; wave w: gsub=w>>1,
// rsub=w&1; lane: g2=lane>>5, j=lane&31; g=q2*4+gsub*2+g2; 128 rows/wave.
// Per row: 8 shfl -> own-head select -> 3 shfl -> 1 exp -> 3 shfl broadcast
// -> 16 acc FMA into head-permuted slots.
// ---------------------------------------------------------------------------
__global__ __launch_bounds__(256, 4) void attn7_kernel(
    const float* __restrict__ qc_g, const float* __restrict__ kn_g,
    const float* __restrict__ vn_g,
    const float* __restrict__ cache_k, const float* __restrict__ cache_v,
    float* __restrict__ pmss, float* __restrict__ pacc)
{
    const int t = threadIdx.x;
    const int w = t >> 6, lane = t & 63;
    const int g2 = lane >> 5, j = lane & 31;
    const int o3 = j & 3;
    const int bid = blockIdx.x;
    const int q2 = bid & 1, split = (bid >> 1) & 15, b = bid >> 5;
    const int gsub = w >> 1, rsub = w & 1;
    const int g = q2 * 4 + gsub * 2 + g2;
    const int row0 = split * 256 + rsub * 128;

    float4 q[4];
    const float* qb = qc_g + (size_t)b * 4096 + (size_t)g * 512 + j * 4;
#pragma unroll
    for (int h = 0; h < 4; ++h) q[h] = *(const float4*)(qb + h * 128);

    float m_s = -1e30f, ss_s = 0.f;
    float4 acc[4];   // slot s holds head (o3^s)
#pragma unroll
    for (int s = 0; s < 4; ++s) acc[s] = make_float4(0.f, 0.f, 0.f, 0.f);

    auto process = [&](const float4 kf, const float4 vf) {
        float d[4];
#pragma unroll
        for (int h = 0; h < 4; ++h)
            d[h] = fmaf(q[h].x, kf.x, fmaf(q[h].y, kf.y,
                   fmaf(q[h].z, kf.z, q[h].w * kf.w)));
        d[0] += __shfl_xor(d[0], 1); d[1] += __shfl_xor(d[1], 1);
        d[2] += __shfl_xor(d[2], 1); d[3] += __shfl_xor(d[3], 1);
        d[0] += __shfl_xor(d[0], 2); d[1] += __shfl_xor(d[1], 2);
        d[2] += __shfl_xor(d[2], 2); d[3] += __shfl_xor(d[3], 2);
        // select this lane's head (o3): static 2-bit select, no scratch
        const float t0 = (o3 & 1) ? d[1] : d[0];
        const float t1 = (o3 & 1) ? d[3] : d[2];
        float dsc = (o3 & 2) ? t1 : t0;
        dsc += __shfl_xor(dsc, 4);
        dsc += __shfl_xor(dsc, 8);
        dsc += __shfl_xor(dsc, 16);
        // online softmax for ONE head; rescale path rare (wave-any)
        if (__any(dsc - m_s > 8.0f)) {
            const float nm = fmaxf(m_s, dsc);
            const float c  = __expf(m_s - nm);
            m_s = nm; ss_s *= c;
            const float c1 = __shfl_xor(c, 1);
            const float c2 = __shfl_xor(c, 2);
            const float c3 = __shfl_xor(c1, 2);
            acc[0].x *= c;  acc[0].y *= c;  acc[0].z *= c;  acc[0].w *= c;
            acc[1].x *= c1; acc[1].y *= c1; acc[1].z *= c1; acc[1].w *= c1;
            acc[2].x *= c2; acc[2].y *= c2; acc[2].z *= c2; acc[2].w *= c2;
            acc[3].x *= c3; acc[3].y *= c3; acc[3].z *= c3; acc[3].w *= c3;
        }
        const float pe = __expf(dsc - m_s);   // <= e^8
        ss_s += pe;
        const float p1 = __shfl_xor(pe, 1);
        const float p2 = __shfl_xor(pe, 2);
        const float p3 = __shfl_xor(p1, 2);
        acc[0].x = fmaf(pe, vf.x, acc[0].x); acc[0].y = fmaf(pe, vf.y, acc[0].y);
        acc[0].z = fmaf(pe, vf.z, acc[0].z); acc[0].w = fmaf(pe, vf.w, acc[0].w);
        acc[1].x = fmaf(p1, vf.x, acc[1].x); acc[1].y = fmaf(p1, vf.y, acc[1].y);
        acc[1].z = fmaf(p1, vf.z, acc[1].z); acc[1].w = fmaf(p1, vf.w, acc[1].w);
        acc[2].x = fmaf(p2, vf.x, acc[2].x); acc[2].y = fmaf(p2, vf.y, acc[2].y);
        acc[2].z = fmaf(p2, vf.z, acc[2].z); acc[2].w = fmaf(p2, vf.w, acc[2].w);
        acc[3].x = fmaf(p3, vf.x, acc[3].x); acc[3].y = fmaf(p3, vf.y, acc[3].y);
        acc[3].z = fmaf(p3, vf.z, acc[3].z); acc[3].w = fmaf(p3, vf.w, acc[3].w);
    };

    const size_t cbase = ((size_t)b * 4096 + row0) * 1024 + (size_t)g * 128 + j * 4;
    const float* kp = cache_k + cbase;
    const float* vp = cache_v + cbase;

    const bool lastw = (split == 15) && (rsub == 1);   // owns row 4095
    const int n = lastw ? 127 : 128;

    // zero-mov 4-slot ping-pong pipeline; nontemporal stream loads
    float4 kA, vA, kB, vB, kC, vC, kD, vD;
    kA = ntload4(kp);        vA = ntload4(vp);
    kB = ntload4(kp + 1024); vB = ntload4(vp + 1024);
    int i = 0;
    for (; i + 4 <= n; i += 4) {
        const float* k2 = kp + (size_t)(i + 2) * 1024;
        const float* v2 = vp + (size_t)(i + 2) * 1024;
        kC = ntload4(k2);        vC = ntload4(v2);
        kD = ntload4(k2 + 1024); vD = ntload4(v2 + 1024);
        process(kA, vA);
        process(kB, vB);
        if (i + 6 <= n) {
            const float* k4 = kp + (size_t)(i + 4) * 1024;
            const float* v4 = vp + (size_t)(i + 4) * 1024;
            kA = ntload4(k4);        vA = ntload4(v4);
            kB = ntload4(k4 + 1024); vB = ntload4(v4 + 1024);
        } else if (i + 5 <= n) {
            const float* k4 = kp + (size_t)(i + 4) * 1024;
            const float* v4 = vp + (size_t)(i + 4) * 1024;
            kA = ntload4(k4); vA = ntload4(v4);
        }
        process(kC, vC);
        process(kD, vD);
    }
    if (i < n)     process(kA, vA);
    if (i + 1 < n) process(kB, vB);
    if (i + 2 < n) {
        const float4 kf = ntload4(kp + (size_t)(i + 2) * 1024);
        const float4 vf = ntload4(vp + (size_t)(i + 2) * 1024);
        process(kf, vf);
    }
    if (lastw) {   // row 4095: freshly roped new-token k / new v
        const float4 kf = *(const float4*)(kn_g + (size_t)b * 1024 + (size_t)g * 128 + j * 4);
        const float4 vf = *(const float4*)(vn_g + (size_t)b * 1024 + (size_t)g * 128 + j * 4);
        process(kf, vf);
    }

    // partials: idx = (((b*16+split)*2+rsub)*8 + g)*4 + h; un-permute slots
    const int pidx = (((b * 16 + split) * 2 + rsub) * 8 + g) * 4;
#pragma unroll
    for (int s = 0; s < 4; ++s) {
        const int head = o3 ^ s;
        *(float4*)(pacc + (size_t)(pidx + head) * 128 + j * 4) = acc[s];
    }
    if (j < 4) {   // lane o3==j holds head j's (m, ss)
        pmss[(size_t)(pidx + j) * 2]     = m_s;
        pmss[(size_t)(pidx + j) * 2 + 1] = ss_s;
    }
}

// ---------------------------------------------------------------------------
// Merge 32 partials per (b,g,h). Block=(b,g), 128 thr: h=t>>5, jj=t&31.
// ---------------------------------------------------------------------------
__global__ __launch_bounds__(128) void attn_combine_kernel(
    const float* __restrict__ pmss, const float* __restrict__ pacc,
    float* __restrict__ a_ws)
{
    const int bg = blockIdx.x, t = threadIdx.x;
    const int h = t >> 5, jj = t & 31;
    const int b = bg >> 3, g = bg & 7;

    float M = -1e30f;
#pragma unroll
    for (int s = 0; s < 16; ++s)
#pragma unroll
        for (int r = 0; r < 2; ++r) {
            const int idx = (((b * 16 + s) * 2 + r) * 8 + g) * 4 + h;
            M = fmaxf(M, pmss[(size_t)idx * 2]);
        }
    float SS = 0.f;
    float4 o = make_float4(0.f, 0.f, 0.f, 0.f);
#pragma unroll
    for (int s = 0; s < 16; ++s)
#pragma unroll
        for (int r = 0; r < 2; ++r) {
            const int idx = (((b * 16 + s) * 2 + r) * 8 + g) * 4 + h;
            const float wgt = __expf(pmss[(size_t)idx * 2] - M);
            SS = fmaf(pmss[(size_t)idx * 2 + 1], wgt, SS);
            const float4 a = *(const float4*)(pacc + (size_t)idx * 128 + jj * 4);
            o.x = fmaf(a.x, wgt, o.x);
            o.y = fmaf(a.y, wgt, o.y);
            o.z = fmaf(a.z, wgt, o.z);
            o.w = fmaf(a.w, wgt, o.w);
        }
    const float inv = 1.f / SS;
    o.x *= inv; o.y *= inv; o.z *= inv; o.w *= inv;
    *(float4*)&a_ws[(size_t)b * 4096 + (size_t)(g * 4 + h) * 128 + jj * 4] = o;
}

__global__ __launch_bounds__(256) void out_combine_kernel(
    const float* __restrict__ part, float* __restrict__ out)
{
    const int i4 = (blockIdx.x * 256 + threadIdx.x) * 4;
    float4 v = make_float4(0.f, 0.f, 0.f, 0.f);
#pragma unroll
    for (int s = 0; s < 16; ++s) {
        const float4 a = *(const float4*)(part + (size_t)s * 131072 + i4);
        v.x += a.x; v.y += a.y; v.z += a.z; v.w += a.w;
    }
    *(float4*)(out + i4) = v;
}

extern "C" void kernel_launch(void* const* d_in, const int* in_sizes, int n_in,
                              void* d_out, int out_size, void* d_ws, size_t ws_size,
                              hipStream_t stream)
{
    const float* x       = (const float*)d_in[0];
    const float* freqs   = (const float*)d_in[1];
    const float* cache_k = (const float*)d_in[2];
    const float* cache_v = (const float*)d_in[3];
    const float* wq      = (const float*)d_in[4];
    const float* wk      = (const float*)d_in[5];
    const float* wv      = (const float*)d_in[6];
    const float* wo      = (const float*)d_in[7];

    float* out = (float*)d_out;
    float* ws  = (float*)d_ws;
    float* part_qkv = ws;                    // 3145728
    float* qc_g     = ws + 3145728;          // 131072
    float* kn_g     = ws + 3276800;          // 32768
    float* vn_g     = ws + 3309568;          // 32768
    float* pmss     = ws + 3342336;          // 65536
    float* pacc     = ws + 3407872;          // 4194304
    float* a_ws     = ws + 7602176;          // 131072
    float* part_out = ws + 7733248;          // 2097152

    gemv_qkv_kernel<<<1536, 256, 0, stream>>>(wq, wk, wv, x, part_qkv);
    qkv_combine_kernel<<<192, 256, 0, stream>>>(part_qkv, freqs, qc_g, kn_g, vn_g);
    attn7_kernel<<<1024, 256, 0, stream>>>(qc_g, kn_g, vn_g, cache_k, cache_v, pmss, pacc);
    attn_combine_kernel<<<256, 128, 0, stream>>>(pmss, pacc, a_ws);
    gemv_out_kernel<<<1024, 256, 0, stream>>>(wo, a_ws, part_out);
    out_combine_kernel<<<128, 256, 0, stream>>>(part_out, out);
}